// Round 1
// baseline (506.928 us; speedup 1.0000x reference)
//
#include <hip/hip_runtime.h>
#include <math.h>

#define NN 4096
#define DD 256
#define HH 4

// k_agg tiling
#define ROWS 64
#define JB 32
#define SPLIT 8

__device__ __forceinline__ float elu_fast(float v) {
  return v > 0.f ? v : __expf(v) - 1.f;
}

// ---------------- zero h_pass accumulator ----------------
__global__ void k_zero(float* __restrict__ hp) {
  int idx = blockIdx.x * 256 + threadIdx.x;           // 1024 blocks -> 262144 float4
  float4 z = make_float4(0.f, 0.f, 0.f, 0.f);
  ((float4*)hp)[idx] = z;
}

// ---------------- s1[h][i] = h_i . a1_h ; s2[h][i] = h_i . a2_h ----------------
__global__ void k_scores(const float* __restrict__ x, const float* __restrict__ a,
                         const float* __restrict__ cwp, const float* __restrict__ cbp,
                         float* __restrict__ s1, float* __restrict__ s2) {
  const int lane = threadIdx.x & 63;
  const int wave = threadIdx.x >> 6;
  const int node = blockIdx.x * 4 + wave;
  const float cw = cwp[0], cb = cbp[0];
  const float4 xv = *(const float4*)(x + (size_t)node * DD + lane * 4);
  float4 hv;
  hv.x = xv.x * cw + cb; hv.y = xv.y * cw + cb;
  hv.z = xv.z * cw + cb; hv.w = xv.w * cw + cb;
  float p1[HH], p2[HH];
#pragma unroll
  for (int h = 0; h < HH; h++) {
    const float4 a1 = *(const float4*)(a + h * 512 + lane * 4);
    const float4 a2 = *(const float4*)(a + h * 512 + 256 + lane * 4);
    p1[h] = hv.x * a1.x + hv.y * a1.y + hv.z * a1.z + hv.w * a1.w;
    p2[h] = hv.x * a2.x + hv.y * a2.y + hv.z * a2.z + hv.w * a2.w;
  }
#pragma unroll
  for (int off = 32; off; off >>= 1) {
#pragma unroll
    for (int h = 0; h < HH; h++) {
      p1[h] += __shfl_xor(p1[h], off);
      p2[h] += __shfl_xor(p2[h], off);
    }
  }
  if (lane == 0) {
#pragma unroll
    for (int h = 0; h < HH; h++) {
      s1[h * NN + node] = p1[h];
      s2[h * NN + node] = p2[h];
    }
  }
}

// ---------------- M[h] = max_j s2[h][j] ----------------
__global__ void k_maxs2(const float* __restrict__ s2, float* __restrict__ M) {
  const int h = blockIdx.x;
  float m = -1e30f;
  for (int j = threadIdx.x; j < NN; j += 256) m = fmaxf(m, s2[h * NN + j]);
#pragma unroll
  for (int off = 32; off; off >>= 1) m = fmaxf(m, __shfl_xor(m, off));
  __shared__ float red[4];
  const int lane = threadIdx.x & 63, wave = threadIdx.x >> 6;
  if (lane == 0) red[wave] = m;
  __syncthreads();
  if (threadIdx.x == 0)
    M[h] = fmaxf(fmaxf(red[0], red[1]), fmaxf(red[2], red[3]));
}

// ---------------- Z[h][i] = sum_j adj * exp(elu(s1+s2_j) - B) ; B = elu(s1+M) ----------------
__global__ void k_z(const int* __restrict__ adj, const float* __restrict__ s1,
                    const float* __restrict__ s2, const float* __restrict__ Mb,
                    float* __restrict__ Bb, float* __restrict__ Zb) {
  const int i = blockIdx.x;
  float s1v[HH], Bv[HH], z[HH];
#pragma unroll
  for (int h = 0; h < HH; h++) {
    s1v[h] = s1[h * NN + i];
    Bv[h] = elu_fast(s1v[h] + Mb[h]);
    z[h] = 0.f;
  }
  const int* arow = adj + (size_t)i * NN;
  for (int j = threadIdx.x; j < NN; j += 256) {
    if (arow[j] > 0) {
#pragma unroll
      for (int h = 0; h < HH; h++) {
        float e = elu_fast(s1v[h] + s2[h * NN + j]);
        z[h] += __expf(e - Bv[h]);
      }
    }
  }
#pragma unroll
  for (int h = 0; h < HH; h++) {
#pragma unroll
    for (int off = 32; off; off >>= 1) z[h] += __shfl_xor(z[h], off);
  }
  __shared__ float red[4][HH];
  const int lane = threadIdx.x & 63, wave = threadIdx.x >> 6;
  if (lane == 0) {
#pragma unroll
    for (int h = 0; h < HH; h++) red[wave][h] = z[h];
  }
  __syncthreads();
  if (threadIdx.x == 0) {
#pragma unroll
    for (int h = 0; h < HH; h++) {
      Zb[h * NN + i] = red[0][h] + red[1][h] + red[2][h] + red[3][h];
      Bb[h * NN + i] = Bv[h];
    }
  }
}

// ---------------- hp += W @ h  (W recomputed on the fly) ----------------
__global__ __launch_bounds__(256) void k_agg(
    const int* __restrict__ adj, const float* __restrict__ x,
    const float* __restrict__ cwp, const float* __restrict__ cbp,
    const float* __restrict__ s1, const float* __restrict__ s2,
    const float* __restrict__ Bb, const float* __restrict__ Zb,
    float* __restrict__ hp) {
  __shared__ __align__(16) float Wt[JB][ROWS];       // 8 KB   Wt[jj][ii]
  __shared__ __align__(16) float hl[JB][DD];         // 32 KB  hl[jj][d]
  __shared__ float sS1[HH][ROWS], sB[HH][ROWS], sZi[HH][ROWS];  // 3 KB

  const int tid = threadIdx.x;
  const int rb = blockIdx.x / SPLIT;
  const int sp = blockIdx.x % SPLIT;
  const int i0 = rb * ROWS;
  const float cw = cwp[0], cb = cbp[0];

  {  // preload per-row stats: 256 threads = 4 heads x 64 rows
    const int r = tid & 63, h = tid >> 6;
    const float zv = Zb[h * NN + i0 + r];
    sS1[h][r] = s1[h * NN + i0 + r];
    sB[h][r] = Bb[h * NN + i0 + r];
    sZi[h][r] = zv > 0.f ? 0.25f / zv : 0.f;
  }

  float acc[8][8];
#pragma unroll
  for (int r = 0; r < 8; r++)
#pragma unroll
    for (int c = 0; c < 8; c++) acc[r][c] = 0.f;

  const int tr = tid >> 5;   // 0..7  (row group of 8)
  const int tc = tid & 31;   // 0..31 (col group of 8)
  const int jlo = sp * (NN / SPLIT);
  const int jhi = jlo + (NN / SPLIT);

  for (int j0 = jlo; j0 < jhi; j0 += JB) {
    __syncthreads();
    // stage h tile: 32 rows x 256 cols as float4 (2048 vec4)
#pragma unroll
    for (int k = 0; k < 8; k++) {
      const int v = tid + k * 256;
      const int jj = v >> 6, d4 = v & 63;
      const float4 xv = *(const float4*)(x + (size_t)(j0 + jj) * DD + d4 * 4);
      float4 hv;
      hv.x = xv.x * cw + cb; hv.y = xv.y * cw + cb;
      hv.z = xv.z * cw + cb; hv.w = xv.w * cw + cb;
      *(float4*)&hl[jj][d4 * 4] = hv;
    }
    // scores: 64 rows x 32 cols
#pragma unroll
    for (int k = 0; k < 8; k++) {
      const int v = tid + k * 256;
      const int jj = v & 31, ii = v >> 5;
      const int aj = adj[(size_t)(i0 + ii) * NN + j0 + jj];
      float w = 0.f;
      if (aj > 0) {
#pragma unroll
        for (int h = 0; h < HH; h++) {
          const float e = elu_fast(sS1[h][ii] + s2[h * NN + j0 + jj]);
          w += __expf(e - sB[h][ii]) * sZi[h][ii];
        }
      }
      Wt[jj][ii] = w;
    }
    __syncthreads();
    // accumulate: outer product, 8x8 per thread
#pragma unroll 4
    for (int jj = 0; jj < JB; jj++) {
      const float4 w0 = *(const float4*)&Wt[jj][tr * 8];
      const float4 w1 = *(const float4*)&Wt[jj][tr * 8 + 4];
      const float4 h0 = *(const float4*)&hl[jj][tc * 8];
      const float4 h1 = *(const float4*)&hl[jj][tc * 8 + 4];
      const float wr[8] = {w0.x, w0.y, w0.z, w0.w, w1.x, w1.y, w1.z, w1.w};
      const float hc[8] = {h0.x, h0.y, h0.z, h0.w, h1.x, h1.y, h1.z, h1.w};
#pragma unroll
      for (int r = 0; r < 8; r++)
#pragma unroll
        for (int c = 0; c < 8; c++) acc[r][c] += wr[r] * hc[c];
    }
  }

#pragma unroll
  for (int r = 0; r < 8; r++) {
    const size_t row = (size_t)(i0 + tr * 8 + r) * DD + tc * 8;
#pragma unroll
    for (int c = 0; c < 8; c++) atomicAdd(&hp[row + c], acc[r][c]);
  }
}

// ---------------- out = elu(0.5*hp + 0.5*h) / rownorm + bias ----------------
__global__ void k_epi(const float* __restrict__ hp, const float* __restrict__ x,
                      const float* __restrict__ cwp, const float* __restrict__ cbp,
                      const float* __restrict__ bias, float* __restrict__ out) {
  const int lane = threadIdx.x & 63, wave = threadIdx.x >> 6;
  const int i = blockIdx.x * 4 + wave;
  const float cw = cwp[0], cb = cbp[0];
  float o[4];
  float ss = 0.f;
#pragma unroll
  for (int k = 0; k < 4; k++) {
    const int d = lane + 64 * k;
    const float hv = x[(size_t)i * DD + d] * cw + cb;
    float v = 0.5f * hp[(size_t)i * DD + d] + 0.5f * hv;
    v = v > 0.f ? v : expm1f(v);
    o[k] = v;
    ss += v * v;
  }
#pragma unroll
  for (int off = 32; off; off >>= 1) ss += __shfl_xor(ss, off);
  const float inv = 1.f / fmaxf(sqrtf(ss), 1e-12f);
#pragma unroll
  for (int k = 0; k < 4; k++) {
    const int d = lane + 64 * k;
    out[(size_t)i * DD + d] = o[k] * inv + bias[d];
  }
}

extern "C" void kernel_launch(void* const* d_in, const int* in_sizes, int n_in,
                              void* d_out, int out_size, void* d_ws, size_t ws_size,
                              hipStream_t stream) {
  const float* x = (const float*)d_in[0];
  const int* adj = (const int*)d_in[1];
  const float* cw = (const float*)d_in[2];
  const float* cb = (const float*)d_in[3];
  const float* a = (const float*)d_in[4];
  const float* bias = (const float*)d_in[5];
  float* out = (float*)d_out;
  float* ws = (float*)d_ws;

  float* s1 = ws;            // H*N = 16384
  float* s2 = ws + 16384;    // H*N
  float* Zb = ws + 32768;    // H*N
  float* Bb = ws + 49152;    // H*N
  float* Mb = ws + 65536;    // H (padded)
  float* hp = ws + 65792;    // N*D = 1048576   total ~4.45 MB

  hipLaunchKernelGGL(k_zero, dim3(1024), dim3(256), 0, stream, hp);
  hipLaunchKernelGGL(k_scores, dim3(1024), dim3(256), 0, stream, x, a, cw, cb, s1, s2);
  hipLaunchKernelGGL(k_maxs2, dim3(HH), dim3(256), 0, stream, s2, Mb);
  hipLaunchKernelGGL(k_z, dim3(NN), dim3(256), 0, stream, adj, s1, s2, Mb, Bb, Zb);
  hipLaunchKernelGGL(k_agg, dim3((NN / ROWS) * SPLIT), dim3(256), 0, stream,
                     adj, x, cw, cb, s1, s2, Bb, Zb, hp);
  hipLaunchKernelGGL(k_epi, dim3(1024), dim3(256), 0, stream, hp, x, cw, cb, bias, out);
}

// Round 2
// 217.485 us; speedup vs baseline: 2.3309x; 2.3309x over previous
//
#include <hip/hip_runtime.h>
#include <math.h>

#define NN 4096
#define DD 256
#define HH 4
#define SPLIT 8
#define BM 64
#define BK 64
#define STR 72   // LDS row stride in bf16 elems (144 B: breaks 16-row bank alignment)

typedef short short8 __attribute__((ext_vector_type(8)));
typedef float float4v __attribute__((ext_vector_type(4)));

__device__ __forceinline__ unsigned short f2bf(float f) {
  unsigned u = __float_as_uint(f);
  u += 0x7FFF + ((u >> 16) & 1);   // RNE
  return (unsigned short)(u >> 16);
}

// ---------------- zero hp (atomic fallback path only) ----------------
__global__ void k_zero(float* __restrict__ hp) {
  int idx = blockIdx.x * 256 + threadIdx.x;
  ((float4*)hp)[idx] = make_float4(0.f, 0.f, 0.f, 0.f);
}

// ---------------- hbfT[d][j] = bf16(x[j][d]*cw+cb)  (B-operand, transposed) ----------------
__global__ void k_prep(const float* __restrict__ x, const float* __restrict__ cwp,
                       const float* __restrict__ cbp, unsigned short* __restrict__ hbfT) {
  __shared__ unsigned short t[64 * 257];
  const int tid = threadIdx.x;
  const int j0 = blockIdx.x * 64;
  const float cw = cwp[0], cb = cbp[0];
  for (int jj = 0; jj < 64; jj++) {
    float v = x[(size_t)(j0 + jj) * DD + tid] * cw + cb;
    t[jj * 257 + tid] = f2bf(v);
  }
  __syncthreads();
  const int jj = tid & 63, dq = tid >> 6;
  for (int k = 0; k < 64; k++) {
    const int d = k * 4 + dq;
    hbfT[(size_t)d * NN + j0 + jj] = t[jj * 257 + d];
  }
}

// ---------------- s1[h][i] = h_i . a1_h ; s2[h][i] = h_i . a2_h ----------------
__global__ void k_scores(const float* __restrict__ x, const float* __restrict__ a,
                         const float* __restrict__ cwp, const float* __restrict__ cbp,
                         float* __restrict__ s1, float* __restrict__ s2) {
  const int lane = threadIdx.x & 63;
  const int wave = threadIdx.x >> 6;
  const int node = blockIdx.x * 4 + wave;
  const float cw = cwp[0], cb = cbp[0];
  const float4 xv = *(const float4*)(x + (size_t)node * DD + lane * 4);
  float4 hv;
  hv.x = xv.x * cw + cb; hv.y = xv.y * cw + cb;
  hv.z = xv.z * cw + cb; hv.w = xv.w * cw + cb;
  float p1[HH], p2[HH];
#pragma unroll
  for (int h = 0; h < HH; h++) {
    const float4 a1 = *(const float4*)(a + h * 512 + lane * 4);
    const float4 a2 = *(const float4*)(a + h * 512 + 256 + lane * 4);
    p1[h] = hv.x * a1.x + hv.y * a1.y + hv.z * a1.z + hv.w * a1.w;
    p2[h] = hv.x * a2.x + hv.y * a2.y + hv.z * a2.z + hv.w * a2.w;
  }
#pragma unroll
  for (int off = 32; off; off >>= 1) {
#pragma unroll
    for (int h = 0; h < HH; h++) {
      p1[h] += __shfl_xor(p1[h], off);
      p2[h] += __shfl_xor(p2[h], off);
    }
  }
  if (lane == 0) {
#pragma unroll
    for (int h = 0; h < HH; h++) {
      s1[h * NN + node] = p1[h];
      s2[h * NN + node] = p2[h];
    }
  }
}

// ---------------- M[h] = max_j s2[h][j] ----------------
__global__ void k_maxs2(const float* __restrict__ s2, float* __restrict__ M) {
  const int h = blockIdx.x;
  float m = -1e30f;
  for (int j = threadIdx.x; j < NN; j += 256) m = fmaxf(m, s2[h * NN + j]);
#pragma unroll
  for (int off = 32; off; off >>= 1) m = fmaxf(m, __shfl_xor(m, off));
  __shared__ float red[4];
  const int lane = threadIdx.x & 63, wave = threadIdx.x >> 6;
  if (lane == 0) red[wave] = m;
  __syncthreads();
  if (threadIdx.x == 0)
    M[h] = fmaxf(fmaxf(red[0], red[1]), fmaxf(red[2], red[3]));
}

// ---------------- Z[h][i] = sum_j adj * exp(elu(s1+s2_j) - B) ; B = elu(s1+M) ----------------
__global__ void k_z(const int* __restrict__ adj, const float* __restrict__ s1,
                    const float* __restrict__ s2, const float* __restrict__ Mb,
                    float* __restrict__ Bb, float* __restrict__ Zb) {
  const int i = blockIdx.x;
  float s1v[HH], Bv[HH], z[HH];
#pragma unroll
  for (int h = 0; h < HH; h++) {
    s1v[h] = s1[h * NN + i];
    const float t = s1v[h] + Mb[h];
    Bv[h] = t > 0.f ? t : __expf(t) - 1.f;
    z[h] = 0.f;
  }
  const int4* arow = (const int4*)(adj + (size_t)i * NN);
  for (int j4 = threadIdx.x; j4 < NN / 4; j4 += 256) {
    const int4 av = arow[j4];
#pragma unroll
    for (int h = 0; h < HH; h++) {
      const float4 sv = *(const float4*)(s2 + h * NN + j4 * 4);
      float t, e;
      t = s1v[h] + sv.x; e = t > 0.f ? t : __expf(t) - 1.f;
      z[h] += av.x > 0 ? __expf(e - Bv[h]) : 0.f;
      t = s1v[h] + sv.y; e = t > 0.f ? t : __expf(t) - 1.f;
      z[h] += av.y > 0 ? __expf(e - Bv[h]) : 0.f;
      t = s1v[h] + sv.z; e = t > 0.f ? t : __expf(t) - 1.f;
      z[h] += av.z > 0 ? __expf(e - Bv[h]) : 0.f;
      t = s1v[h] + sv.w; e = t > 0.f ? t : __expf(t) - 1.f;
      z[h] += av.w > 0 ? __expf(e - Bv[h]) : 0.f;
    }
  }
#pragma unroll
  for (int h = 0; h < HH; h++) {
#pragma unroll
    for (int off = 32; off; off >>= 1) z[h] += __shfl_xor(z[h], off);
  }
  __shared__ float red[4][HH];
  const int lane = threadIdx.x & 63, wave = threadIdx.x >> 6;
  if (lane == 0) {
#pragma unroll
    for (int h = 0; h < HH; h++) red[wave][h] = z[h];
  }
  __syncthreads();
  if (threadIdx.x == 0) {
#pragma unroll
    for (int h = 0; h < HH; h++) {
      Zb[h * NN + i] = red[0][h] + red[1][h] + red[2][h] + red[3][h];
      Bb[h * NN + i] = Bv[h];
    }
  }
}

// ---------------- hp = W @ h via bf16 MFMA, W recomputed per tile ----------------
__global__ __launch_bounds__(256) void k_agg(
    const int* __restrict__ adj, const unsigned short* __restrict__ hbfT,
    const float* __restrict__ s1, const float* __restrict__ s2,
    const float* __restrict__ Bb, const float* __restrict__ Zb,
    float* __restrict__ hpOut, int useSplit) {
  __shared__ unsigned short sW[BM * STR];    // A operand: W[ii][jj] bf16
  __shared__ unsigned short sH[DD * STR];    // B operand: h^T[d][jj] bf16
  __shared__ float sS1[HH][BM], sB[HH][BM], sZi[HH][BM], ss2[HH][BK];

  const int tid = threadIdx.x;
  const int w = tid >> 6, lane = tid & 63;
  const int m16 = lane & 15, q = lane >> 4;
  const int rb = blockIdx.x >> 3, sp = blockIdx.x & 7;
  const int i0 = rb * BM;
  const int jlo = sp * (NN / SPLIT);

  {  // per-row stats: 4 waves = 4 heads, 64 lanes = 64 rows
    const float zv = Zb[w * NN + i0 + lane];
    sS1[w][lane] = s1[w * NN + i0 + lane];
    sB[w][lane] = Bb[w * NN + i0 + lane];
    sZi[w][lane] = zv > 0.f ? 0.25f / zv : 0.f;
  }

  float4v acc[4][4];
#pragma unroll
  for (int a = 0; a < 4; a++)
#pragma unroll
    for (int b = 0; b < 4; b++) acc[a][b] = (float4v)0.f;

  for (int kt = 0; kt < (NN / SPLIT) / BK; kt++) {
    const int j0 = jlo + kt * BK;
    __syncthreads();
    ss2[w][lane] = s2[w * NN + j0 + lane];
    {  // stage h^T tile: 256 rows(d) x 64 cols(j) bf16
      const int dbase = tid >> 3, part = tid & 7;
#pragma unroll
      for (int r = 0; r < 8; r++) {
        const int d = dbase + r * 32;
        const float4 v = *(const float4*)(hbfT + (size_t)d * NN + j0 + part * 8);
        *(float4*)(sH + d * STR + part * 8) = v;
      }
    }
    __syncthreads();
    {  // W tile: 64x64
      const int jj = lane;
#pragma unroll
      for (int r = 0; r < 16; r++) {
        const int ii = r * 4 + w;
        const int av = adj[(size_t)(i0 + ii) * NN + j0 + jj];
        float wsum = 0.f;
#pragma unroll
        for (int h = 0; h < HH; h++) {
          const float tv = sS1[h][ii] + ss2[h][jj];
          const float e = tv > 0.f ? tv : __expf(tv) - 1.f;
          wsum += __expf(e - sB[h][ii]) * sZi[h][ii];
        }
        sW[ii * STR + jj] = av > 0 ? f2bf(wsum) : (unsigned short)0;
      }
    }
    __syncthreads();
#pragma unroll
    for (int ks = 0; ks < 2; ks++) {
      const int kb = ks * 32 + q * 8;
      short8 aF[4], bF[4];
#pragma unroll
      for (int it = 0; it < 4; it++)
        aF[it] = *(const short8*)(sW + (it * 16 + m16) * STR + kb);
#pragma unroll
      for (int dt = 0; dt < 4; dt++)
        bF[dt] = *(const short8*)(sH + (w * 64 + dt * 16 + m16) * STR + kb);
#pragma unroll
      for (int it = 0; it < 4; it++)
#pragma unroll
        for (int dt = 0; dt < 4; dt++)
          acc[it][dt] = __builtin_amdgcn_mfma_f32_16x16x32_bf16(aF[it], bF[dt], acc[it][dt], 0, 0, 0);
    }
  }

  // epilogue: C/D layout col=lane&15, row=q*4+reg
  if (useSplit) {
    float* base = hpOut + (size_t)sp * NN * DD;
#pragma unroll
    for (int it = 0; it < 4; it++)
#pragma unroll
      for (int dt = 0; dt < 4; dt++) {
        const int d = w * 64 + dt * 16 + m16;
#pragma unroll
        for (int rg = 0; rg < 4; rg++) {
          const int i = i0 + it * 16 + q * 4 + rg;
          base[(size_t)i * DD + d] = acc[it][dt][rg];
        }
      }
  } else {
#pragma unroll
    for (int it = 0; it < 4; it++)
#pragma unroll
      for (int dt = 0; dt < 4; dt++) {
        const int d = w * 64 + dt * 16 + m16;
#pragma unroll
        for (int rg = 0; rg < 4; rg++) {
          const int i = i0 + it * 16 + q * 4 + rg;
          atomicAdd(&hpOut[(size_t)i * DD + d], acc[it][dt][rg]);
        }
      }
  }
}

// ---------------- out = elu(0.5*mean_splits(hp) + 0.5*h) / rownorm + bias ----------------
__global__ void k_epi(const float* __restrict__ hp, int nsplit,
                      const float* __restrict__ x, const float* __restrict__ cwp,
                      const float* __restrict__ cbp, const float* __restrict__ bias,
                      float* __restrict__ out) {
  const int lane = threadIdx.x & 63, wave = threadIdx.x >> 6;
  const int i = blockIdx.x * 4 + wave;
  const float cw = cwp[0], cb = cbp[0];
  float o[4];
  float ss = 0.f;
#pragma unroll
  for (int k = 0; k < 4; k++) {
    const int d = lane + 64 * k;
    float pv = 0.f;
    for (int s = 0; s < nsplit; s++)
      pv += hp[(size_t)s * NN * DD + (size_t)i * DD + d];
    const float hv = x[(size_t)i * DD + d] * cw + cb;
    float v = 0.5f * pv + 0.5f * hv;
    v = v > 0.f ? v : expm1f(v);
    o[k] = v;
    ss += v * v;
  }
#pragma unroll
  for (int off = 32; off; off >>= 1) ss += __shfl_xor(ss, off);
  const float inv = 1.f / fmaxf(sqrtf(ss), 1e-12f);
#pragma unroll
  for (int k = 0; k < 4; k++) {
    const int d = lane + 64 * k;
    out[(size_t)i * DD + d] = o[k] * inv + bias[d];
  }
}

extern "C" void kernel_launch(void* const* d_in, const int* in_sizes, int n_in,
                              void* d_out, int out_size, void* d_ws, size_t ws_size,
                              hipStream_t stream) {
  const float* x = (const float*)d_in[0];
  const int* adj = (const int*)d_in[1];
  const float* cw = (const float*)d_in[2];
  const float* cb = (const float*)d_in[3];
  const float* a = (const float*)d_in[4];
  const float* bias = (const float*)d_in[5];
  float* out = (float*)d_out;
  float* ws = (float*)d_ws;

  float* s1 = ws;                                  // H*N
  float* s2 = ws + 16384;                          // H*N
  float* Zb = ws + 32768;                          // H*N
  float* Bb = ws + 49152;                          // H*N
  float* Mb = ws + 65536;                          // H (padded to 256)
  unsigned short* hbfT = (unsigned short*)(ws + 65792);  // N*D bf16 = 524288 floats
  float* hp = ws + 65792 + 524288;                 // SPLIT*N*D (split) or N*D (atomic)

  const size_t needSplit = (size_t)(65792 + 524288 + SPLIT * NN * DD) * 4;
  const int useSplit = (ws_size >= needSplit) ? 1 : 0;
  const int nsplit = useSplit ? SPLIT : 1;

  if (!useSplit) hipLaunchKernelGGL(k_zero, dim3(1024), dim3(256), 0, stream, hp);
  hipLaunchKernelGGL(k_prep, dim3(64), dim3(256), 0, stream, x, cw, cb, hbfT);
  hipLaunchKernelGGL(k_scores, dim3(1024), dim3(256), 0, stream, x, a, cw, cb, s1, s2);
  hipLaunchKernelGGL(k_maxs2, dim3(HH), dim3(256), 0, stream, s2, Mb);
  hipLaunchKernelGGL(k_z, dim3(NN), dim3(256), 0, stream, adj, s1, s2, Mb, Bb, Zb);
  hipLaunchKernelGGL(k_agg, dim3((NN / BM) * SPLIT), dim3(256), 0, stream,
                     adj, hbfT, s1, s2, Bb, Zb, hp, useSplit);
  hipLaunchKernelGGL(k_epi, dim3(1024), dim3(256), 0, stream, hp, nsplit, x, cw, cb, bias, out);
}

// Round 3
// 177.994 us; speedup vs baseline: 2.8480x; 1.2219x over previous
//
#include <hip/hip_runtime.h>
#include <math.h>

#define NN 4096
#define DD 256
#define HH 4
#define SPLIT 8
#define BM 64
#define BK 64
#define STR 72   // LDS row stride in bf16 elems (144 B = 36 banks: odd -> conflict-light)

typedef short short8 __attribute__((ext_vector_type(8)));
typedef float float4v __attribute__((ext_vector_type(4)));

__device__ __forceinline__ unsigned short f2bf(float f) {
  unsigned u = __float_as_uint(f);
  u += 0x7FFF + ((u >> 16) & 1);   // RNE
  return (unsigned short)(u >> 16);
}
__device__ __forceinline__ float bf2f(unsigned short s) {
  return __uint_as_float(((unsigned)s) << 16);
}

// ---------------- zero hp (old-path atomic fallback only) ----------------
__global__ void k_zero(float* __restrict__ hp) {
  int idx = blockIdx.x * 256 + threadIdx.x;
  ((float4*)hp)[idx] = make_float4(0.f, 0.f, 0.f, 0.f);
}

// ---------------- hbfT[d][j] = bf16(x[j][d]*cw+cb) ----------------
__global__ void k_prep(const float* __restrict__ x, const float* __restrict__ cwp,
                       const float* __restrict__ cbp, unsigned short* __restrict__ hbfT) {
  __shared__ unsigned short t[64 * 257];
  const int tid = threadIdx.x;
  const int j0 = blockIdx.x * 64;
  const float cw = cwp[0], cb = cbp[0];
  for (int jj = 0; jj < 64; jj++) {
    float v = x[(size_t)(j0 + jj) * DD + tid] * cw + cb;
    t[jj * 257 + tid] = f2bf(v);
  }
  __syncthreads();
  const int jj = tid & 63, dq = tid >> 6;
  for (int k = 0; k < 64; k++) {
    const int d = k * 4 + dq;
    hbfT[(size_t)d * NN + j0 + jj] = t[jj * 257 + d];
  }
}

// ---------------- s1[h][i], s2[h][i] ----------------
__global__ void k_scores(const float* __restrict__ x, const float* __restrict__ a,
                         const float* __restrict__ cwp, const float* __restrict__ cbp,
                         float* __restrict__ s1, float* __restrict__ s2) {
  const int lane = threadIdx.x & 63;
  const int wave = threadIdx.x >> 6;
  const int node = blockIdx.x * 4 + wave;
  const float cw = cwp[0], cb = cbp[0];
  const float4 xv = *(const float4*)(x + (size_t)node * DD + lane * 4);
  float4 hv;
  hv.x = xv.x * cw + cb; hv.y = xv.y * cw + cb;
  hv.z = xv.z * cw + cb; hv.w = xv.w * cw + cb;
  float p1[HH], p2[HH];
#pragma unroll
  for (int h = 0; h < HH; h++) {
    const float4 a1 = *(const float4*)(a + h * 512 + lane * 4);
    const float4 a2 = *(const float4*)(a + h * 512 + 256 + lane * 4);
    p1[h] = hv.x * a1.x + hv.y * a1.y + hv.z * a1.z + hv.w * a1.w;
    p2[h] = hv.x * a2.x + hv.y * a2.y + hv.z * a2.z + hv.w * a2.w;
  }
#pragma unroll
  for (int off = 32; off; off >>= 1) {
#pragma unroll
    for (int h = 0; h < HH; h++) {
      p1[h] += __shfl_xor(p1[h], off);
      p2[h] += __shfl_xor(p2[h], off);
    }
  }
  if (lane == 0) {
#pragma unroll
    for (int h = 0; h < HH; h++) {
      s1[h * NN + node] = p1[h];
      s2[h * NN + node] = p2[h];
    }
  }
}

// ---------------- M[h] = max_j s2[h][j] ----------------
__global__ void k_maxs2(const float* __restrict__ s2, float* __restrict__ M) {
  const int h = blockIdx.x;
  float m = -1e30f;
  for (int j = threadIdx.x; j < NN; j += 256) m = fmaxf(m, s2[h * NN + j]);
#pragma unroll
  for (int off = 32; off; off >>= 1) m = fmaxf(m, __shfl_xor(m, off));
  __shared__ float red[4];
  const int lane = threadIdx.x & 63, wave = threadIdx.x >> 6;
  if (lane == 0) red[wave] = m;
  __syncthreads();
  if (threadIdx.x == 0)
    M[h] = fmaxf(fmaxf(red[0], red[1]), fmaxf(red[2], red[3]));
}

// ========== NEW PATH: fused Z + W in one pass (exp computed once) ==========
// One block per row i. P_h,j kept in LDS as bf16 between the two phases.
__global__ __launch_bounds__(256) void k_zw(
    const int* __restrict__ adj, const float* __restrict__ s1g,
    const float* __restrict__ s2g, const float* __restrict__ Mb,
    unsigned short* __restrict__ Wm) {
  __shared__ unsigned short sP[HH][NN];   // 32 KB
  __shared__ float red[4][HH];
  __shared__ float sZi[HH];

  const int i = blockIdx.x;
  const int tid = threadIdx.x;
  float s1v[HH], Bv[HH], z[HH];
#pragma unroll
  for (int h = 0; h < HH; h++) {
    s1v[h] = s1g[h * NN + i];
    const float t = s1v[h] + Mb[h];
    Bv[h] = t > 0.f ? t : __expf(t) - 1.f;
    z[h] = 0.f;
  }
  const int4* arow = (const int4*)(adj + (size_t)i * NN);
#pragma unroll
  for (int j4 = tid; j4 < NN / 4; j4 += 256) {
    const int4 av = arow[j4];
#pragma unroll
    for (int h = 0; h < HH; h++) {
      const float4 sv = *(const float4*)(s2g + h * NN + j4 * 4);
      float t, e, p0, p1, p2, p3;
      t = s1v[h] + sv.x; e = t > 0.f ? t : __expf(t) - 1.f;
      p0 = av.x > 0 ? __expf(e - Bv[h]) : 0.f;
      t = s1v[h] + sv.y; e = t > 0.f ? t : __expf(t) - 1.f;
      p1 = av.y > 0 ? __expf(e - Bv[h]) : 0.f;
      t = s1v[h] + sv.z; e = t > 0.f ? t : __expf(t) - 1.f;
      p2 = av.z > 0 ? __expf(e - Bv[h]) : 0.f;
      t = s1v[h] + sv.w; e = t > 0.f ? t : __expf(t) - 1.f;
      p3 = av.w > 0 ? __expf(e - Bv[h]) : 0.f;
      z[h] += (p0 + p1) + (p2 + p3);
      ushort4 pk;
      pk.x = f2bf(p0); pk.y = f2bf(p1); pk.z = f2bf(p2); pk.w = f2bf(p3);
      *(ushort4*)&sP[h][j4 * 4] = pk;
    }
  }
#pragma unroll
  for (int h = 0; h < HH; h++) {
#pragma unroll
    for (int off = 32; off; off >>= 1) z[h] += __shfl_xor(z[h], off);
  }
  const int lane = tid & 63, wave = tid >> 6;
  if (lane == 0) {
#pragma unroll
    for (int h = 0; h < HH; h++) red[wave][h] = z[h];
  }
  __syncthreads();
  if (tid < HH) {
    const float zt = red[0][tid] + red[1][tid] + red[2][tid] + red[3][tid];
    sZi[tid] = zt > 0.f ? 0.25f / zt : 0.f;
  }
  __syncthreads();
  float Zi[HH];
#pragma unroll
  for (int h = 0; h < HH; h++) Zi[h] = sZi[h];

  unsigned short* wrow = Wm + (size_t)i * NN;
#pragma unroll
  for (int j4 = tid; j4 < NN / 4; j4 += 256) {
    float w0 = 0.f, w1 = 0.f, w2 = 0.f, w3 = 0.f;
#pragma unroll
    for (int h = 0; h < HH; h++) {
      const ushort4 pk = *(const ushort4*)&sP[h][j4 * 4];
      w0 += bf2f(pk.x) * Zi[h];
      w1 += bf2f(pk.y) * Zi[h];
      w2 += bf2f(pk.z) * Zi[h];
      w3 += bf2f(pk.w) * Zi[h];
    }
    ushort4 wk;
    wk.x = f2bf(w0); wk.y = f2bf(w1); wk.z = f2bf(w2); wk.w = f2bf(w3);
    *(ushort4*)&wrow[j4 * 4] = wk;
  }
}

// ========== NEW PATH: pure bf16 GEMM hp = W @ h ==========
__global__ __launch_bounds__(256) void k_gemm(
    const unsigned short* __restrict__ Wm, const unsigned short* __restrict__ hbfT,
    float* __restrict__ hpOut) {
  __shared__ __align__(16) unsigned short sW[BM * STR];   // 9 KB
  __shared__ __align__(16) unsigned short sH[DD * STR];   // 36 KB

  const int tid = threadIdx.x;
  const int w = tid >> 6, lane = tid & 63;
  const int m16 = lane & 15, q = lane >> 4;
  const int rb = blockIdx.x >> 3, sp = blockIdx.x & 7;
  const int i0 = rb * BM;
  const int jlo = sp * (NN / SPLIT);
  const int r0 = tid >> 3;   // 0..31
  const int c0 = tid & 7;    // 0..7

  float4v acc[4][4];
#pragma unroll
  for (int a = 0; a < 4; a++)
#pragma unroll
    for (int b = 0; b < 4; b++) acc[a][b] = (float4v)0.f;

  for (int kt = 0; kt < (NN / SPLIT) / BK; kt++) {
    const int j0 = jlo + kt * BK;
    __syncthreads();
#pragma unroll
    for (int r = 0; r < 2; r++) {
      const int row = r * 32 + r0;
      *(float4*)(sW + row * STR + c0 * 8) =
          *(const float4*)(Wm + (size_t)(i0 + row) * NN + j0 + c0 * 8);
    }
#pragma unroll
    for (int r = 0; r < 8; r++) {
      const int d = r * 32 + r0;
      *(float4*)(sH + d * STR + c0 * 8) =
          *(const float4*)(hbfT + (size_t)d * NN + j0 + c0 * 8);
    }
    __syncthreads();
#pragma unroll
    for (int ks = 0; ks < 2; ks++) {
      const int kb = ks * 32 + q * 8;
      short8 aF[4], bF[4];
#pragma unroll
      for (int it = 0; it < 4; it++)
        aF[it] = *(const short8*)(sW + (it * 16 + m16) * STR + kb);
#pragma unroll
      for (int dt = 0; dt < 4; dt++)
        bF[dt] = *(const short8*)(sH + (w * 64 + dt * 16 + m16) * STR + kb);
#pragma unroll
      for (int it = 0; it < 4; it++)
#pragma unroll
        for (int dt = 0; dt < 4; dt++)
          acc[it][dt] = __builtin_amdgcn_mfma_f32_16x16x32_bf16(aF[it], bF[dt], acc[it][dt], 0, 0, 0);
    }
  }

  float* base = hpOut + (size_t)sp * NN * DD;
#pragma unroll
  for (int it = 0; it < 4; it++)
#pragma unroll
    for (int dt = 0; dt < 4; dt++) {
      const int d = w * 64 + dt * 16 + m16;
#pragma unroll
      for (int rg = 0; rg < 4; rg++) {
        const int i = i0 + it * 16 + q * 4 + rg;
        base[(size_t)i * DD + d] = acc[it][dt][rg];
      }
    }
}

// ========== OLD PATH (fallback when ws is small): round-2 kernels ==========
__global__ void k_z(const int* __restrict__ adj, const float* __restrict__ s1,
                    const float* __restrict__ s2, const float* __restrict__ Mb,
                    float* __restrict__ Bb, float* __restrict__ Zb) {
  const int i = blockIdx.x;
  float s1v[HH], Bv[HH], z[HH];
#pragma unroll
  for (int h = 0; h < HH; h++) {
    s1v[h] = s1[h * NN + i];
    const float t = s1v[h] + Mb[h];
    Bv[h] = t > 0.f ? t : __expf(t) - 1.f;
    z[h] = 0.f;
  }
  const int4* arow = (const int4*)(adj + (size_t)i * NN);
  for (int j4 = threadIdx.x; j4 < NN / 4; j4 += 256) {
    const int4 av = arow[j4];
#pragma unroll
    for (int h = 0; h < HH; h++) {
      const float4 sv = *(const float4*)(s2 + h * NN + j4 * 4);
      float t, e;
      t = s1v[h] + sv.x; e = t > 0.f ? t : __expf(t) - 1.f;
      z[h] += av.x > 0 ? __expf(e - Bv[h]) : 0.f;
      t = s1v[h] + sv.y; e = t > 0.f ? t : __expf(t) - 1.f;
      z[h] += av.y > 0 ? __expf(e - Bv[h]) : 0.f;
      t = s1v[h] + sv.z; e = t > 0.f ? t : __expf(t) - 1.f;
      z[h] += av.z > 0 ? __expf(e - Bv[h]) : 0.f;
      t = s1v[h] + sv.w; e = t > 0.f ? t : __expf(t) - 1.f;
      z[h] += av.w > 0 ? __expf(e - Bv[h]) : 0.f;
    }
  }
#pragma unroll
  for (int h = 0; h < HH; h++) {
#pragma unroll
    for (int off = 32; off; off >>= 1) z[h] += __shfl_xor(z[h], off);
  }
  __shared__ float red[4][HH];
  const int lane = threadIdx.x & 63, wave = threadIdx.x >> 6;
  if (lane == 0) {
#pragma unroll
    for (int h = 0; h < HH; h++) red[wave][h] = z[h];
  }
  __syncthreads();
  if (threadIdx.x == 0) {
#pragma unroll
    for (int h = 0; h < HH; h++) {
      Zb[h * NN + i] = red[0][h] + red[1][h] + red[2][h] + red[3][h];
      Bb[h * NN + i] = Bv[h];
    }
  }
}

__global__ __launch_bounds__(256) void k_agg_fused(
    const int* __restrict__ adj, const unsigned short* __restrict__ hbfT,
    const float* __restrict__ s1, const float* __restrict__ s2,
    const float* __restrict__ Bb, const float* __restrict__ Zb,
    float* __restrict__ hpOut, int useSplit) {
  __shared__ unsigned short sW[BM * STR];
  __shared__ unsigned short sH[DD * STR];
  __shared__ float sS1[HH][BM], sB[HH][BM], sZi[HH][BM], ss2[HH][BK];

  const int tid = threadIdx.x;
  const int w = tid >> 6, lane = tid & 63;
  const int m16 = lane & 15, q = lane >> 4;
  const int rb = blockIdx.x >> 3, sp = blockIdx.x & 7;
  const int i0 = rb * BM;
  const int jlo = sp * (NN / SPLIT);

  {
    const float zv = Zb[w * NN + i0 + lane];
    sS1[w][lane] = s1[w * NN + i0 + lane];
    sB[w][lane] = Bb[w * NN + i0 + lane];
    sZi[w][lane] = zv > 0.f ? 0.25f / zv : 0.f;
  }

  float4v acc[4][4];
#pragma unroll
  for (int a = 0; a < 4; a++)
#pragma unroll
    for (int b = 0; b < 4; b++) acc[a][b] = (float4v)0.f;

  for (int kt = 0; kt < (NN / SPLIT) / BK; kt++) {
    const int j0 = jlo + kt * BK;
    __syncthreads();
    ss2[w][lane] = s2[w * NN + j0 + lane];
    {
      const int dbase = tid >> 3, part = tid & 7;
#pragma unroll
      for (int r = 0; r < 8; r++) {
        const int d = dbase + r * 32;
        const float4 v = *(const float4*)(hbfT + (size_t)d * NN + j0 + part * 8);
        *(float4*)(sH + d * STR + part * 8) = v;
      }
    }
    __syncthreads();
    {
      const int jj = lane;
#pragma unroll
      for (int r = 0; r < 16; r++) {
        const int ii = r * 4 + w;
        const int av = adj[(size_t)(i0 + ii) * NN + j0 + jj];
        float wsum = 0.f;
#pragma unroll
        for (int h = 0; h < HH; h++) {
          const float tv = sS1[h][ii] + ss2[h][jj];
          const float e = tv > 0.f ? tv : __expf(tv) - 1.f;
          wsum += __expf(e - sB[h][ii]) * sZi[h][ii];
        }
        sW[ii * STR + jj] = av > 0 ? f2bf(wsum) : (unsigned short)0;
      }
    }
    __syncthreads();
#pragma unroll
    for (int ks = 0; ks < 2; ks++) {
      const int kb = ks * 32 + q * 8;
      short8 aF[4], bF[4];
#pragma unroll
      for (int it = 0; it < 4; it++)
        aF[it] = *(const short8*)(sW + (it * 16 + m16) * STR + kb);
#pragma unroll
      for (int dt = 0; dt < 4; dt++)
        bF[dt] = *(const short8*)(sH + (w * 64 + dt * 16 + m16) * STR + kb);
#pragma unroll
      for (int it = 0; it < 4; it++)
#pragma unroll
        for (int dt = 0; dt < 4; dt++)
          acc[it][dt] = __builtin_amdgcn_mfma_f32_16x16x32_bf16(aF[it], bF[dt], acc[it][dt], 0, 0, 0);
    }
  }

  if (useSplit) {
    float* base = hpOut + (size_t)sp * NN * DD;
#pragma unroll
    for (int it = 0; it < 4; it++)
#pragma unroll
      for (int dt = 0; dt < 4; dt++) {
        const int d = w * 64 + dt * 16 + m16;
#pragma unroll
        for (int rg = 0; rg < 4; rg++) {
          const int i = i0 + it * 16 + q * 4 + rg;
          base[(size_t)i * DD + d] = acc[it][dt][rg];
        }
      }
  } else {
#pragma unroll
    for (int it = 0; it < 4; it++)
#pragma unroll
      for (int dt = 0; dt < 4; dt++) {
        const int d = w * 64 + dt * 16 + m16;
#pragma unroll
        for (int rg = 0; rg < 4; rg++) {
          const int i = i0 + it * 16 + q * 4 + rg;
          atomicAdd(&hpOut[(size_t)i * DD + d], acc[it][dt][rg]);
        }
      }
  }
}

// ---------------- epilogue ----------------
__global__ void k_epi(const float* __restrict__ hp, int nsplit,
                      const float* __restrict__ x, const float* __restrict__ cwp,
                      const float* __restrict__ cbp, const float* __restrict__ bias,
                      float* __restrict__ out) {
  const int lane = threadIdx.x & 63, wave = threadIdx.x >> 6;
  const int i = blockIdx.x * 4 + wave;
  const float cw = cwp[0], cb = cbp[0];
  float o[4];
  float ss = 0.f;
#pragma unroll
  for (int k = 0; k < 4; k++) {
    const int d = lane + 64 * k;
    float pv = 0.f;
    for (int s = 0; s < nsplit; s++)
      pv += hp[(size_t)s * NN * DD + (size_t)i * DD + d];
    const float hv = x[(size_t)i * DD + d] * cw + cb;
    float v = 0.5f * pv + 0.5f * hv;
    v = v > 0.f ? v : expm1f(v);
    o[k] = v;
    ss += v * v;
  }
#pragma unroll
  for (int off = 32; off; off >>= 1) ss += __shfl_xor(ss, off);
  const float inv = 1.f / fmaxf(sqrtf(ss), 1e-12f);
#pragma unroll
  for (int k = 0; k < 4; k++) {
    const int d = lane + 64 * k;
    out[(size_t)i * DD + d] = o[k] * inv + bias[d];
  }
}

extern "C" void kernel_launch(void* const* d_in, const int* in_sizes, int n_in,
                              void* d_out, int out_size, void* d_ws, size_t ws_size,
                              hipStream_t stream) {
  const float* x = (const float*)d_in[0];
  const int* adj = (const int*)d_in[1];
  const float* cw = (const float*)d_in[2];
  const float* cb = (const float*)d_in[3];
  const float* a = (const float*)d_in[4];
  const float* bias = (const float*)d_in[5];
  float* out = (float*)d_out;
  float* ws = (float*)d_ws;

  // New-path layout (floats): s1 | s2 | Mb | hbfT | Wm | hp(split)
  const size_t newNeed = (size_t)(16384 * 2 + 256 + 524288 + 8388608 + 8388608) * 4;

  if (ws_size >= newNeed) {
    float* s1 = ws;
    float* s2 = ws + 16384;
    float* Mb = ws + 32768;
    unsigned short* hbfT = (unsigned short*)(ws + 33024);
    unsigned short* Wm = (unsigned short*)(ws + 33024 + 524288);
    float* hp = ws + 33024 + 524288 + 8388608;

    hipLaunchKernelGGL(k_prep, dim3(64), dim3(256), 0, stream, x, cw, cb, hbfT);
    hipLaunchKernelGGL(k_scores, dim3(1024), dim3(256), 0, stream, x, a, cw, cb, s1, s2);
    hipLaunchKernelGGL(k_maxs2, dim3(HH), dim3(256), 0, stream, s2, Mb);
    hipLaunchKernelGGL(k_zw, dim3(NN), dim3(256), 0, stream, adj, s1, s2, Mb, Wm);
    hipLaunchKernelGGL(k_gemm, dim3((NN / BM) * SPLIT), dim3(256), 0, stream, Wm, hbfT, hp);
    hipLaunchKernelGGL(k_epi, dim3(1024), dim3(256), 0, stream, hp, SPLIT, x, cw, cb, bias, out);
  } else {
    // round-2 fallback
    float* s1 = ws;
    float* s2 = ws + 16384;
    float* Zb = ws + 32768;
    float* Bb = ws + 49152;
    float* Mb = ws + 65536;
    unsigned short* hbfT = (unsigned short*)(ws + 65792);
    float* hp = ws + 65792 + 524288;

    const size_t needSplit = (size_t)(65792 + 524288 + SPLIT * NN * DD) * 4;
    const int useSplit = (ws_size >= needSplit) ? 1 : 0;
    const int nsplit = useSplit ? SPLIT : 1;

    if (!useSplit) hipLaunchKernelGGL(k_zero, dim3(1024), dim3(256), 0, stream, hp);
    hipLaunchKernelGGL(k_prep, dim3(64), dim3(256), 0, stream, x, cw, cb, hbfT);
    hipLaunchKernelGGL(k_scores, dim3(1024), dim3(256), 0, stream, x, a, cw, cb, s1, s2);
    hipLaunchKernelGGL(k_maxs2, dim3(HH), dim3(256), 0, stream, s2, Mb);
    hipLaunchKernelGGL(k_z, dim3(NN), dim3(256), 0, stream, adj, s1, s2, Mb, Bb, Zb);
    hipLaunchKernelGGL(k_agg_fused, dim3((NN / BM) * SPLIT), dim3(256), 0, stream,
                       adj, hbfT, s1, s2, Bb, Zb, hp, useSplit);
    hipLaunchKernelGGL(k_epi, dim3(1024), dim3(256), 0, stream, hp, nsplit, x, cw, cb, bias, out);
  }
}